// Round 2
// baseline (1581.680 us; speedup 1.0000x reference)
//
#include <hip/hip_runtime.h>
#include <hip/hip_bf16.h>

#define N_    64
#define CIN   128
#define COUT  256
#define T_    128
#define V_    25
#define TOUT  64
#define VOUT  13
#define EPS_  1e-5f

typedef __hip_bfloat16 bf16;

__device__ __forceinline__ float ldv(const bf16* p)  { return __bfloat162float(*p); }
__device__ __forceinline__ float ldv(const float* p) { return *p; }
__device__ __forceinline__ void  stv(bf16* p, float v)  { *p = __float2bfloat16(v); }
__device__ __forceinline__ void  stv(float* p, float v) { *p = v; }

// Reduce (s, ss) across a 256-thread block; valid in thread 0 afterwards.
__device__ __forceinline__ void blockReduce2(float& s, float& ss) {
    __shared__ float ls[4], lss[4];
    int lane = threadIdx.x & 63, wid = threadIdx.x >> 6;
#pragma unroll
    for (int o = 32; o > 0; o >>= 1) {
        s  += __shfl_down(s, o, 64);
        ss += __shfl_down(ss, o, 64);
    }
    if (lane == 0) { ls[wid] = s; lss[wid] = ss; }
    __syncthreads();
    if (threadIdx.x == 0) {
        s  = ls[0] + ls[1] + ls[2] + ls[3];
        ss = lss[0] + lss[1] + lss[2] + lss[3];
    }
}

// ---- dtype detector: scan first 8192 bf16-interpreted slots of x.
// Genuine bf16 N(0,1): exponent <= ~129. fp32 reinterpreted: low halves are
// ~uniform 16-bit -> ~25% have exponent >= 192. flag: 0 = bf16, 1 = fp32.
__global__ void detect_k(const unsigned short* __restrict__ xr, int* flag) {
    __shared__ int cnt;
    if (threadIdx.x == 0) cnt = 0;
    __syncthreads();
    int c = 0;
    for (int i = threadIdx.x; i < 8192; i += 256) {
        int e = (xr[i] >> 7) & 0xFF;
        if (e >= 192) c++;
    }
    atomicAdd(&cnt, c);
    __syncthreads();
    if (threadIdx.x == 0) flag[0] = (cnt > 0) ? 1 : 0;
}

// ---- BN1: one block per input channel; writes affine a1,b1 directly ----
template<int MODE, typename DT>
__global__ void bn1_k(const int* __restrict__ flag, const DT* __restrict__ x,
                      const DT* __restrict__ gamma, const DT* __restrict__ beta,
                      float* __restrict__ a1, float* __restrict__ b1) {
    if (flag[0] != MODE) return;
    int c = blockIdx.x;
    float s = 0.f, ss = 0.f;
    for (int i = threadIdx.x; i < N_ * T_ * V_; i += 256) {
        int n = i / (T_ * V_);
        int j = i % (T_ * V_);
        float v = ldv(&x[((size_t)n * CIN + c) * (T_ * V_) + j]);
        s += v; ss += v * v;
    }
    blockReduce2(s, ss);
    if (threadIdx.x == 0) {
        float cnt = (float)(N_ * T_ * V_);
        float mean = s / cnt;
        float var = ss / cnt - mean * mean;
        float a = ldv(&gamma[c]) * rsqrtf(var + EPS_);
        a1[c] = a;
        b1[c] = ldv(&beta[c]) - mean * a;
    }
}

// ---- fused shift_in + BN1 + conv3x3 s2 p1 + bias + relu -> y (stored in d_out) ----
template<int MODE, typename DT>
__global__ __launch_bounds__(256) void conv_k(const int* __restrict__ flag,
                                              const DT* __restrict__ x,
                                              const DT* __restrict__ wgt,
                                              const DT* __restrict__ bias,
                                              const DT* __restrict__ s_in,
                                              const float* __restrict__ a1,
                                              const float* __restrict__ b1,
                                              DT* __restrict__ y) {
    if (flag[0] != MODE) return;
    __shared__ float sh[CIN * 3 * 28];   // [ci][kt][vv], vv = v_in+1 in [0,27), pad 28
    const int to = blockIdx.x, n = blockIdx.y;
    const int tid = threadIdx.x;

    for (int e = tid; e < CIN * 3 * 27; e += 256) {
        int ci = e / 81;
        int r = e % 81;
        int tt = r / 27;
        int vv = r % 27;
        int t_in = 2 * to + tt - 1;
        int v_in = vv - 1;
        float hv = 0.f;
        if (t_in >= 0 && t_in < T_ && v_in >= 0 && v_in < V_) {
            float s = ldv(&s_in[ci]);
            float tsrc = (float)t_in + s;
            float f0 = floorf(tsrc);
            float frac = tsrc - f0;
            int i0 = (int)f0;
            int i1 = i0 + 1;
            float w0 = (i0 >= 0 && i0 < T_) ? (1.f - frac) : 0.f;
            float w1 = (i1 >= 0 && i1 < T_) ? frac : 0.f;
            int i0c = min(max(i0, 0), T_ - 1);
            int i1c = min(max(i1, 0), T_ - 1);
            const DT* xc = x + ((size_t)n * CIN + ci) * (T_ * V_);
            float xv = w0 * ldv(&xc[i0c * V_ + v_in]) + w1 * ldv(&xc[i1c * V_ + v_in]);
            hv = a1[ci] * xv + b1[ci] * (w0 + w1);
        }
        sh[(ci * 3 + tt) * 28 + vv] = hv;
    }
    __syncthreads();

    const int co = tid;  // 256 threads = 256 output channels
    float acc[VOUT];
#pragma unroll
    for (int i = 0; i < VOUT; i++) acc[i] = 0.f;

    const DT* wb = wgt + (size_t)co * CIN * 9;
    for (int ci = 0; ci < CIN; ci++) {
        float wr[9];
#pragma unroll
        for (int k = 0; k < 9; k++) wr[k] = ldv(&wb[ci * 9 + k]);
#pragma unroll
        for (int kt = 0; kt < 3; kt++) {
            const float* row = &sh[(ci * 3 + kt) * 28];
            float r[27];
#pragma unroll
            for (int j = 0; j < 27; j++) r[j] = row[j];  // broadcast LDS reads
#pragma unroll
            for (int vo = 0; vo < VOUT; vo++) {
                acc[vo] += wr[kt * 3 + 0] * r[2 * vo + 0]
                         + wr[kt * 3 + 1] * r[2 * vo + 1]
                         + wr[kt * 3 + 2] * r[2 * vo + 2];
            }
        }
    }
    float bi = ldv(&bias[co]);
    DT* yp = y + (((size_t)n * COUT + co) * TOUT + to) * VOUT;
#pragma unroll
    for (int vo = 0; vo < VOUT; vo++) stv(&yp[vo], fmaxf(acc[vo] + bi, 0.f));
}

// ---- BN2 stats over z = shift_out(y): one block per output channel ----
template<int MODE, typename DT>
__global__ void bn2_k(const int* __restrict__ flag, const DT* __restrict__ y,
                      const DT* __restrict__ s_out,
                      const DT* __restrict__ gamma, const DT* __restrict__ beta,
                      float* __restrict__ a2, float* __restrict__ b2) {
    if (flag[0] != MODE) return;
    int co = blockIdx.x;
    float sv = ldv(&s_out[co]);
    float s = 0.f, ss = 0.f;
    for (int i = threadIdx.x; i < N_ * TOUT * VOUT; i += 256) {
        int n = i / (TOUT * VOUT);
        int r = i % (TOUT * VOUT);
        int to = r / VOUT;
        int vo = r % VOUT;
        float tsrc = (float)to + sv;
        float f0 = floorf(tsrc);
        float frac = tsrc - f0;
        int i0 = (int)f0, i1 = i0 + 1;
        float w0 = (i0 >= 0 && i0 < TOUT) ? (1.f - frac) : 0.f;
        float w1 = (i1 >= 0 && i1 < TOUT) ? frac : 0.f;
        int i0c = min(max(i0, 0), TOUT - 1);
        int i1c = min(max(i1, 0), TOUT - 1);
        const DT* yc = y + ((size_t)n * COUT + co) * (TOUT * VOUT);
        float z = w0 * ldv(&yc[i0c * VOUT + vo]) + w1 * ldv(&yc[i1c * VOUT + vo]);
        s += z; ss += z * z;
    }
    blockReduce2(s, ss);
    if (threadIdx.x == 0) {
        float cnt = (float)(N_ * TOUT * VOUT);
        float mean = s / cnt;
        float var = ss / cnt - mean * mean;
        float a = ldv(&gamma[co]) * rsqrtf(var + EPS_);
        a2[co] = a;
        b2[co] = ldv(&beta[co]) - mean * a;
    }
}

// ---- in-place: out = a2 * shift_out(y) + b2, per (n,co) plane via LDS ----
template<int MODE, typename DT>
__global__ void final_k(const int* __restrict__ flag, DT* __restrict__ y,
                        const DT* __restrict__ s_out,
                        const float* __restrict__ a2, const float* __restrict__ b2) {
    if (flag[0] != MODE) return;
    __shared__ float pl[TOUT * VOUT];
    int co = blockIdx.x, n = blockIdx.y;
    DT* base = y + ((size_t)n * COUT + co) * (TOUT * VOUT);
    for (int i = threadIdx.x; i < TOUT * VOUT; i += 256) pl[i] = ldv(&base[i]);
    __syncthreads();
    float sv = ldv(&s_out[co]);
    float A = a2[co], B = b2[co];
    for (int i = threadIdx.x; i < TOUT * VOUT; i += 256) {
        int to = i / VOUT, vo = i % VOUT;
        float tsrc = (float)to + sv;
        float f0 = floorf(tsrc);
        float frac = tsrc - f0;
        int i0 = (int)f0, i1 = i0 + 1;
        float w0 = (i0 >= 0 && i0 < TOUT) ? (1.f - frac) : 0.f;
        float w1 = (i1 >= 0 && i1 < TOUT) ? frac : 0.f;
        int i0c = min(max(i0, 0), TOUT - 1);
        int i1c = min(max(i1, 0), TOUT - 1);
        float z = w0 * pl[i0c * VOUT + vo] + w1 * pl[i1c * VOUT + vo];
        stv(&base[i], A * z + B);
    }
}

extern "C" void kernel_launch(void* const* d_in, const int* in_sizes, int n_in,
                              void* d_out, int out_size, void* d_ws, size_t ws_size,
                              hipStream_t stream) {
    // ws: flag (aligned 256B) | a1[128] | b1[128] | a2[256] | b2[256]  (~3.3 KB)
    int*   flag = (int*)d_ws;
    float* a1 = (float*)((char*)d_ws + 256);
    float* b1 = a1 + 128;
    float* a2 = b1 + 128;
    float* b2 = a2 + 256;

    detect_k<<<1, 256, 0, stream>>>((const unsigned short*)d_in[0], flag);

    // MODE 0: bf16 tensors
    {
        const bf16* x    = (const bf16*)d_in[0];
        const bf16* g1   = (const bf16*)d_in[1];
        const bf16* be1  = (const bf16*)d_in[2];
        const bf16* sin_ = (const bf16*)d_in[3];
        const bf16* w    = (const bf16*)d_in[4];
        const bf16* cb   = (const bf16*)d_in[5];
        const bf16* sout = (const bf16*)d_in[6];
        const bf16* g2   = (const bf16*)d_in[7];
        const bf16* be2  = (const bf16*)d_in[8];
        bf16* y = (bf16*)d_out;
        bn1_k<0, bf16><<<dim3(CIN), 256, 0, stream>>>(flag, x, g1, be1, a1, b1);
        conv_k<0, bf16><<<dim3(TOUT, N_), 256, 0, stream>>>(flag, x, w, cb, sin_, a1, b1, y);
        bn2_k<0, bf16><<<dim3(COUT), 256, 0, stream>>>(flag, y, sout, g2, be2, a2, b2);
        final_k<0, bf16><<<dim3(COUT, N_), 256, 0, stream>>>(flag, y, sout, a2, b2);
    }
    // MODE 1: fp32 tensors
    {
        const float* x    = (const float*)d_in[0];
        const float* g1   = (const float*)d_in[1];
        const float* be1  = (const float*)d_in[2];
        const float* sin_ = (const float*)d_in[3];
        const float* w    = (const float*)d_in[4];
        const float* cb   = (const float*)d_in[5];
        const float* sout = (const float*)d_in[6];
        const float* g2   = (const float*)d_in[7];
        const float* be2  = (const float*)d_in[8];
        float* y = (float*)d_out;
        bn1_k<1, float><<<dim3(CIN), 256, 0, stream>>>(flag, x, g1, be1, a1, b1);
        conv_k<1, float><<<dim3(TOUT, N_), 256, 0, stream>>>(flag, x, w, cb, sin_, a1, b1, y);
        bn2_k<1, float><<<dim3(COUT), 256, 0, stream>>>(flag, y, sout, g2, be2, a2, b2);
        final_k<1, float><<<dim3(COUT, N_), 256, 0, stream>>>(flag, y, sout, a2, b2);
    }
}